// Round 1
// baseline (510.894 us; speedup 1.0000x reference)
//
#include <hip/hip_runtime.h>
#include <math.h>

// Problem constants (match reference)
#define BH 128
#define S  8192
#define D  64
#define ALPHA_F 0.999f

// Tiling
#define CHUNK   1024
#define NCHUNK  (S / CHUNK)   // 8
#define PSTRIDE 72            // floats per partial record: [0]=m, [1]=z, [4..67]=o[64]

// Kernel 1: per-(bh, chunk) partial exp-weighted attention.
// 256 threads = 16 groups x 16 lanes. Each group of 16 lanes computes the
// 64-dim q.k dot for one s per iteration (float4/lane, shfl_xor reduce).
__global__ __launch_bounds__(256) void partial_kernel(
    const float* __restrict__ q,     // [BH,1,D]
    const float* __restrict__ k,     // [BH,S,D]
    const float* __restrict__ v,     // [BH,S,D]
    const float* __restrict__ mask,  // [BH,1,S]
    float* __restrict__ ws)
{
    const int blk   = blockIdx.x;
    const int bh    = blk / NCHUNK;
    const int chunk = blk % NCHUNK;
    const int s0    = chunk * CHUNK;
    const int t     = threadIdx.x;
    const int lid   = t & 15;   // lane within 16-lane group
    const int g     = t >> 4;   // group 0..15
    const int wave  = t >> 6;   // wave 0..3

    __shared__ float sc[CHUNK];        // scores, then probs (4 KiB)
    __shared__ float red[8];           // [0..3]=per-wave max, [4..7]=per-wave z
    __shared__ float o_parts[16][64];  // 4 KiB

    // q fragment for this lane (reused across all s)
    const float4 q4 = *reinterpret_cast<const float4*>(q + bh * D + lid * 4);

    const float* kb = k + (size_t)bh * S * D;
    const float* vb = v + (size_t)bh * S * D;
    const float* mb = mask + (size_t)bh * S;

    // ---- Phase 1: scores (dot + mask) into LDS; track local max ----
    float lmax = -INFINITY;
    #pragma unroll 4
    for (int it = 0; it < CHUNK / 16; ++it) {
        const int sl = it * 16 + g;           // local s index
        const int s  = s0 + sl;
        const float4 k4 = *reinterpret_cast<const float4*>(kb + (size_t)s * D + lid * 4);
        float d = q4.x * k4.x + q4.y * k4.y + q4.z * k4.z + q4.w * k4.w;
        // reduce across the 16 lanes of this group (stays within aligned subgroup)
        d += __shfl_xor(d, 1);
        d += __shfl_xor(d, 2);
        d += __shfl_xor(d, 4);
        d += __shfl_xor(d, 8);
        d += mb[s];                           // same addr across group -> broadcast
        if (lid == 0) sc[sl] = d;
        lmax = fmaxf(lmax, d);
    }

    // ---- block max ----
    #pragma unroll
    for (int off = 1; off < 64; off <<= 1) lmax = fmaxf(lmax, __shfl_xor(lmax, off));
    if ((t & 63) == 0) red[wave] = lmax;
    __syncthreads();
    const float M = fmaxf(fmaxf(red[0], red[1]), fmaxf(red[2], red[3]));

    // ---- Phase 2: probs in LDS + per-thread z ----
    float zl = 0.f;
    #pragma unroll
    for (int s = t; s < CHUNK; s += 256) {
        const float p = __expf(sc[s] - M);
        sc[s] = p;
        zl += p;
    }
    #pragma unroll
    for (int off = 1; off < 64; off <<= 1) zl += __shfl_xor(zl, off);
    if ((t & 63) == 0) red[4 + wave] = zl;
    __syncthreads();

    // ---- Phase 3: o accumulation (coalesced float4 v loads) ----
    const int dq = t & 15;   // which float4 of the 64 dims
    const int sr = t >> 4;   // s-row 0..15
    float4 o4 = {0.f, 0.f, 0.f, 0.f};
    #pragma unroll 4
    for (int it = 0; it < CHUNK / 16; ++it) {
        const int sl = it * 16 + sr;
        const float p = sc[sl];               // broadcast within 16 lanes
        const float4 v4 = *reinterpret_cast<const float4*>(vb + (size_t)(s0 + sl) * D + dq * 4);
        o4.x += p * v4.x;
        o4.y += p * v4.y;
        o4.z += p * v4.z;
        o4.w += p * v4.w;
    }
    o_parts[sr][dq * 4 + 0] = o4.x;
    o_parts[sr][dq * 4 + 1] = o4.y;
    o_parts[sr][dq * 4 + 2] = o4.z;
    o_parts[sr][dq * 4 + 3] = o4.w;
    __syncthreads();

    // ---- Final block reduce + write partial record ----
    if (t < 64) {
        float acc = 0.f;
        #pragma unroll
        for (int r = 0; r < 16; ++r) acc += o_parts[r][t];
        float* rec = ws + (size_t)blk * PSTRIDE;
        rec[4 + t] = acc;
        if (t == 0) {
            rec[0] = M;
            rec[1] = red[4] + red[5] + red[6] + red[7];
        }
    }
}

// Kernel 2: combine the NCHUNK partials per bh, apply push step, write output.
__global__ __launch_bounds__(64) void reduce_kernel(
    const float* __restrict__ q_push,  // [BH,1,D]
    const float* __restrict__ k_push,  // [BH,1,D]
    const float* __restrict__ v_push,  // [BH,1,D]
    const float* __restrict__ ws,
    float* __restrict__ out)           // [BH,1,D]
{
    const int bh = blockIdx.x;
    const int t  = threadIdx.x;  // 0..63 == d
    const float* base = ws + (size_t)bh * NCHUNK * PSTRIDE;

    float M = -INFINITY;
    #pragma unroll
    for (int c = 0; c < NCHUNK; ++c) M = fmaxf(M, base[c * PSTRIDE]);

    float z = 0.f, o = 0.f;
    #pragma unroll
    for (int c = 0; c < NCHUNK; ++c) {
        const float w = __expf(base[c * PSTRIDE] - M);
        z += w * base[c * PSTRIDE + 1];
        o += w * base[c * PSTRIDE + 4 + t];
    }

    // push-step dot(q_push, k_push) across the 64 lanes
    float pd = q_push[bh * D + t] * k_push[bh * D + t];
    #pragma unroll
    for (int off = 1; off < 64; off <<= 1) pd += __shfl_xor(pd, off);
    const float p = __expf(pd - M);

    // out = (alpha*QKV_exp + p*v_push) / (alpha*Z + p)
    out[bh * D + t] = (ALPHA_F * o + p * v_push[bh * D + t]) / (ALPHA_F * z + p);
}

extern "C" void kernel_launch(void* const* d_in, const int* in_sizes, int n_in,
                              void* d_out, int out_size, void* d_ws, size_t ws_size,
                              hipStream_t stream) {
    const float* q      = (const float*)d_in[0];
    const float* k      = (const float*)d_in[1];
    const float* v      = (const float*)d_in[2];
    const float* q_push = (const float*)d_in[3];
    const float* k_push = (const float*)d_in[4];
    const float* v_push = (const float*)d_in[5];
    const float* mask   = (const float*)d_in[6];
    float* ws  = (float*)d_ws;
    float* out = (float*)d_out;

    partial_kernel<<<dim3(BH * NCHUNK), dim3(256), 0, stream>>>(q, k, v, mask, ws);
    reduce_kernel<<<dim3(BH), dim3(64), 0, stream>>>(q_push, k_push, v_push, ws, out);
}